// Round 2
// baseline (532.116 us; speedup 1.0000x reference)
//
#include <hip/hip_runtime.h>

#define NB   2
#define NHD  8
#define BH   16
#define HD   16
#define N0   9216
#define N1   2304
#define N2   576
#define W0_  96
#define W1_  48
#define W2_  24
#define M_TOT 18432
#define TEMP 0.25f

// ---------------- projection GEMM: dst[(b,h,n,d)] = sum_c A[m][c] * W[o][c] ----------------
__global__ __launch_bounds__(256) void k_proj(const float* __restrict__ x, const float* __restrict__ tg,
    const float* __restrict__ Wq, const float* __restrict__ Wk, const float* __restrict__ Wv,
    float* __restrict__ q0, float* __restrict__ k0, float* __restrict__ v0)
{
    __shared__ __align__(16) float At[16][68];   // [k][row]
    __shared__ __align__(16) float Wt[16][132];  // [k][o]
    const int t = threadIdx.x;
    const int which = blockIdx.y;
    const float* A  = (which==0)? x : tg;
    const float* Wm = (which==0)? Wq : (which==1? Wk : Wv);
    float* dst      = (which==0)? q0 : (which==1? k0 : v0);
    const int m0 = blockIdx.x * 64;
    const int tx = t & 15, ty = t >> 4;

    float acc[4][8];
#pragma unroll
    for(int i=0;i<4;i++)
#pragma unroll
        for(int j=0;j<8;j++) acc[i][j]=0.f;

    const int ar = t>>2, akq = (t&3)*4;
    const int wo = t>>1, wkq = (t&1)*8;

    for(int kc=0;kc<128;kc+=16){
        // stage A tile (transposed): At[k][row]
        float4 av = *(const float4*)(A + (size_t)(m0+ar)*128 + kc + akq);
        At[akq+0][ar] = av.x;
        At[akq+1][ar] = av.y;
        At[akq+2][ar] = av.z;
        At[akq+3][ar] = av.w;
        // stage W tile (transposed): Wt[k][o]
        float4 w0 = *(const float4*)(Wm + (size_t)wo*128 + kc + wkq);
        float4 w1 = *(const float4*)(Wm + (size_t)wo*128 + kc + wkq + 4);
        Wt[wkq+0][wo] = w0.x; Wt[wkq+1][wo] = w0.y;
        Wt[wkq+2][wo] = w0.z; Wt[wkq+3][wo] = w0.w;
        Wt[wkq+4][wo] = w1.x; Wt[wkq+5][wo] = w1.y;
        Wt[wkq+6][wo] = w1.z; Wt[wkq+7][wo] = w1.w;
        __syncthreads();
#pragma unroll
        for(int kk=0;kk<16;kk++){
            float4 a4 = *(const float4*)&At[kk][ty*4];
            float4 wa = *(const float4*)&Wt[kk][tx*4];
            float4 wb = *(const float4*)&Wt[kk][64 + tx*4];
            float avr[4] = {a4.x,a4.y,a4.z,a4.w};
            float wvr[8] = {wa.x,wa.y,wa.z,wa.w, wb.x,wb.y,wb.z,wb.w};
#pragma unroll
            for(int i=0;i<4;i++)
#pragma unroll
                for(int j=0;j<8;j++) acc[i][j] += avr[i]*wvr[j];
        }
        __syncthreads();
    }
#pragma unroll
    for(int i=0;i<4;i++){
        int m = m0 + ty*4 + i;
        int b = m / N0; int n = m - b*N0;
#pragma unroll
        for(int j=0;j<8;j++){
            int o = (j<4)? (tx*4+j) : (64 + tx*4 + (j-4));
            int h = o>>4, d = o&15;
            dst[((size_t)(b*NHD+h)*N0 + n)*16 + d] = acc[i][j];
        }
    }
}

// ---------------- 2x2 average pooling, treats q/k/v contiguously as [48][Nin][16] ----------------
__global__ __launch_bounds__(256) void k_pool(const float4* __restrict__ src, float4* __restrict__ dst,
                                              int Win, int Nin, int Nout, int total)
{
    int tid = blockIdx.x*256 + threadIdx.x;
    if (tid >= total) return;
    int d4 = tid & 3;
    int rest = tid >> 2;
    int n = rest % Nout; int g = rest / Nout;
    int Wout = Win>>1;
    int yo = n / Wout, xo = n - yo*Wout;
    int cbase = (2*yo)*Win + 2*xo;
    const float4* s = src + (size_t)g*Nin*4;
    float4 a = s[(cbase      )*4 + d4];
    float4 b = s[(cbase+1    )*4 + d4];
    float4 c = s[(cbase+Win  )*4 + d4];
    float4 d = s[(cbase+Win+1)*4 + d4];
    float4 o;
    o.x = 0.25f*(a.x+b.x+c.x+d.x);
    o.y = 0.25f*(a.y+b.y+c.y+d.y);
    o.z = 0.25f*(a.z+b.z+c.z+d.z);
    o.w = 0.25f*(a.w+b.w+c.w+d.w);
    dst[((size_t)g*Nout + n)*4 + d4] = o;
}

// ---------------- level-2 full attention + top-16 ----------------
__global__ __launch_bounds__(256) void k_attn2(const float* __restrict__ q2, const float* __restrict__ k2,
    const float* __restrict__ v2, float* __restrict__ msg2, int* __restrict__ idx2)
{
    __shared__ __align__(16) float kT[16][577];
    const int bh = blockIdx.x;
    const int qt = blockIdx.y;
    const int t = threadIdx.x;
    // stage k2 transposed: kT[d][m]
    const float4* kg = (const float4*)(k2 + (size_t)bh*N2*16);
#pragma unroll
    for(int i=0;i<9;i++){
        int f = i*256 + t;          // 2304 float4s
        int m = f>>2, dq = (f&3)*4;
        float4 kv = kg[f];
        kT[dq+0][m]=kv.x; kT[dq+1][m]=kv.y; kT[dq+2][m]=kv.z; kT[dq+3][m]=kv.w;
    }
    __syncthreads();

    const int wv = t>>6, lane = t&63;
    const float4* vg = (const float4*)(v2 + (size_t)bh*N2*16);

    for(int i=0;i<16;i++){
        int q = qt*64 + wv*16 + i;
        const float* qp = q2 + ((size_t)bh*N2 + q)*16;
        float qr[16];
#pragma unroll
        for(int d=0; d<16; d+=4){
            float4 qq = *(const float4*)(qp+d);
            qr[d]=qq.x; qr[d+1]=qq.y; qr[d+2]=qq.z; qr[d+3]=qq.w;
        }
        float ev[9];
        float mx = -1e30f;
#pragma unroll
        for(int t9=0;t9<9;t9++){
            int m = t9*64 + lane;
            float s = 0.f;
#pragma unroll
            for(int d=0;d<16;d++) s += qr[d]*kT[d][m];
            s *= TEMP;
            ev[t9]=s;
            mx = fmaxf(mx, s);
        }
#pragma unroll
        for(int st=1; st<64; st<<=1) mx = fmaxf(mx, __shfl_xor(mx, st));
        float sum=0.f;
#pragma unroll
        for(int t9=0;t9<9;t9++){ ev[t9] = expf(ev[t9]-mx); sum += ev[t9]; }
#pragma unroll
        for(int st=1; st<64; st<<=1) sum += __shfl_xor(sum, st);

        float acc[16];
#pragma unroll
        for(int d=0;d<16;d++) acc[d]=0.f;
#pragma unroll
        for(int t9=0;t9<9;t9++){
            int m = t9*64+lane;
            float e = ev[t9];
#pragma unroll
            for(int dq=0; dq<4; dq++){
                float4 vvv = vg[m*4+dq];
                acc[dq*4+0] += e*vvv.x; acc[dq*4+1] += e*vvv.y;
                acc[dq*4+2] += e*vvv.z; acc[dq*4+3] += e*vvv.w;
            }
        }
#pragma unroll
        for(int st=1; st<64; st<<=1){
#pragma unroll
            for(int d=0;d<16;d++) acc[d] += __shfl_xor(acc[d], st);
        }
        float inv = 1.0f/sum;
        if (lane==0){
            float4* mp = (float4*)(msg2 + ((size_t)bh*N2+q)*16);
#pragma unroll
            for(int dq=0;dq<4;dq++){
                float4 o;
                o.x=acc[dq*4+0]*inv; o.y=acc[dq*4+1]*inv;
                o.z=acc[dq*4+2]*inv; o.w=acc[dq*4+3]*inv;
                mp[dq]=o;
            }
        }
        // top-16 (order of exp == order of scores; ties -> lowest index)
        int* ip = idx2 + ((size_t)bh*N2+q)*16;
        for(int it=0; it<16; it++){
            float bv = ev[0]; int bt=0;
#pragma unroll
            for(int t9=1;t9<9;t9++){ if (ev[t9] > bv){ bv=ev[t9]; bt=t9; } }
            int bm = bt*64 + lane;
#pragma unroll
            for(int st=1; st<64; st<<=1){
                float ov = __shfl_xor(bv, st);
                int   om = __shfl_xor(bm, st);
                if (ov > bv || (ov==bv && om < bm)){ bv=ov; bm=om; }
            }
            if (lane==0) ip[it] = bm;
            int bt9 = bm>>6;
#pragma unroll
            for(int t9=0;t9<9;t9++)
                if (t9==bt9 && (bm & 63) == lane) ev[t9] = -1e30f;
        }
    }
}

// ---------------- level-1 refinement (64 candidates/query) + top-8 ----------------
__global__ __launch_bounds__(256) void k_ref1(const float* __restrict__ q1, const float* __restrict__ k1,
    const float* __restrict__ v1, const float* __restrict__ msg2, const int* __restrict__ idx2,
    float* __restrict__ msg1, int* __restrict__ idx1)
{
    const int gw = blockIdx.x*4 + (threadIdx.x>>6);
    const int lane = threadIdx.x & 63;
    const int bh = gw / N1, n = gw - bh*N1;
    const int y = n / W1_, x = n - y*W1_;
    const int par = (y>>1)*W2_ + (x>>1);
    const int kk = lane>>2, tt = lane&3, dy = tt>>1, dx = tt&1;
    int p = idx2[((size_t)bh*N2+par)*16 + kk];
    int ky = p / W2_, kx = p - ky*W2_;
    int child = (2*ky+dy)*W1_ + 2*kx+dx;

    const float* qp = q1 + ((size_t)bh*N1+n)*16;
    float qr[16];
#pragma unroll
    for(int d=0; d<16; d+=4){
        float4 qq = *(const float4*)(qp+d);
        qr[d]=qq.x; qr[d+1]=qq.y; qr[d+2]=qq.z; qr[d+3]=qq.w;
    }
    const float4* kp = (const float4*)(k1 + ((size_t)bh*N1+child)*16);
    float s = 0.f;
#pragma unroll
    for(int dq=0;dq<4;dq++){
        float4 kv = kp[dq];
        s += qr[dq*4+0]*kv.x + qr[dq*4+1]*kv.y + qr[dq*4+2]*kv.z + qr[dq*4+3]*kv.w;
    }
    s *= TEMP;
    float mx = s;
#pragma unroll
    for(int st=1; st<64; st<<=1) mx = fmaxf(mx, __shfl_xor(mx, st));
    float e = expf(s - mx);
    float sum = e;
#pragma unroll
    for(int st=1; st<64; st<<=1) sum += __shfl_xor(sum, st);

    float acc[16];
    const float4* vp = (const float4*)(v1 + ((size_t)bh*N1+child)*16);
#pragma unroll
    for(int dq=0;dq<4;dq++){
        float4 vv = vp[dq];
        acc[dq*4+0]=e*vv.x; acc[dq*4+1]=e*vv.y; acc[dq*4+2]=e*vv.z; acc[dq*4+3]=e*vv.w;
    }
#pragma unroll
    for(int st=1; st<64; st<<=1){
#pragma unroll
        for(int d=0;d<16;d++) acc[d] += __shfl_xor(acc[d], st);
    }
    float inv = 1.0f/sum;
    if (lane==0){
        const float4* m2 = (const float4*)(msg2 + ((size_t)bh*N2+par)*16);
        float4* m1 = (float4*)(msg1 + ((size_t)bh*N1+n)*16);
#pragma unroll
        for(int dq=0;dq<4;dq++){
            float4 mm = m2[dq];
            float4 o;
            o.x = mm.x + acc[dq*4+0]*inv; o.y = mm.y + acc[dq*4+1]*inv;
            o.z = mm.z + acc[dq*4+2]*inv; o.w = mm.w + acc[dq*4+3]*inv;
            m1[dq]=o;
        }
    }
    // top-8 over the 64 candidates (ties -> lowest candidate position)
    int* ip = idx1 + ((size_t)bh*N1+n)*8;
    float ee = e;
    for(int it=0; it<8; it++){
        float bv = ee; int bj = lane;
#pragma unroll
        for(int st=1; st<64; st<<=1){
            float ov = __shfl_xor(bv, st);
            int   oj = __shfl_xor(bj, st);
            if (ov > bv || (ov==bv && oj < bj)){ bv=ov; bj=oj; }
        }
        int wc = __shfl(child, bj);
        if (lane==0) ip[it] = wc;
        if (lane == bj) ee = -1e30f;
    }
}

// ---------------- level-0 refinement (32 candidates/query), 2 queries per wave ----------------
__global__ __launch_bounds__(256) void k_ref0(const float* __restrict__ q0, const float* __restrict__ k0,
    const float* __restrict__ v0, const float* __restrict__ msg1, const int* __restrict__ idx1,
    float* __restrict__ msg0)
{
    const int gw = blockIdx.x*4 + (threadIdx.x>>6);
    const int lane = threadIdx.x & 63;
    const int sub = lane>>5, j = lane&31;
    const int qi = gw*2 + sub;
    const int bh = qi / N0, n = qi - bh*N0;
    const int y = n / W0_, x = n - y*W0_;
    const int par = (y>>1)*W1_ + (x>>1);
    const int kk = j>>2, tt = j&3, dy = tt>>1, dx = tt&1;
    int p = idx1[((size_t)bh*N1+par)*8 + kk];
    int ky = p / W1_, kx = p - ky*W1_;
    int child = (2*ky+dy)*W0_ + 2*kx+dx;

    const float* qp = q0 + ((size_t)bh*N0+n)*16;
    float qr[16];
#pragma unroll
    for(int d=0; d<16; d+=4){
        float4 qq = *(const float4*)(qp+d);
        qr[d]=qq.x; qr[d+1]=qq.y; qr[d+2]=qq.z; qr[d+3]=qq.w;
    }
    const float4* kp = (const float4*)(k0 + ((size_t)bh*N0+child)*16);
    float s = 0.f;
#pragma unroll
    for(int dq=0;dq<4;dq++){
        float4 kv = kp[dq];
        s += qr[dq*4+0]*kv.x + qr[dq*4+1]*kv.y + qr[dq*4+2]*kv.z + qr[dq*4+3]*kv.w;
    }
    s *= TEMP;
    float mx = s;
#pragma unroll
    for(int st=1; st<32; st<<=1) mx = fmaxf(mx, __shfl_xor(mx, st));
    float e = expf(s - mx);
    float sum = e;
#pragma unroll
    for(int st=1; st<32; st<<=1) sum += __shfl_xor(sum, st);

    float acc[16];
    const float4* vp = (const float4*)(v0 + ((size_t)bh*N0+child)*16);
#pragma unroll
    for(int dq=0;dq<4;dq++){
        float4 vv = vp[dq];
        acc[dq*4+0]=e*vv.x; acc[dq*4+1]=e*vv.y; acc[dq*4+2]=e*vv.z; acc[dq*4+3]=e*vv.w;
    }
#pragma unroll
    for(int st=1; st<32; st<<=1){
#pragma unroll
        for(int d=0;d<16;d++) acc[d] += __shfl_xor(acc[d], st);
    }
    float inv = 1.0f/sum;
    if (j==0){
        int b = bh>>3, h = bh&7;
        const float4* m1 = (const float4*)(msg1 + ((size_t)bh*N1+par)*16);
        float4* mp = (float4*)(msg0 + ((size_t)b*N0+n)*128 + h*16);
#pragma unroll
        for(int dq=0;dq<4;dq++){
            float4 mm = m1[dq];
            float4 o;
            o.x = mm.x + acc[dq*4+0]*inv; o.y = mm.y + acc[dq*4+1]*inv;
            o.z = mm.z + acc[dq*4+2]*inv; o.w = mm.w + acc[dq*4+3]*inv;
            mp[dq]=o;
        }
    }
}

// ---------------- output projection GEMM + bias ----------------
__global__ __launch_bounds__(256) void k_out(const float* __restrict__ msg0, const float* __restrict__ Wo,
    const float* __restrict__ bo, float* __restrict__ out)
{
    __shared__ __align__(16) float At[16][68];
    __shared__ __align__(16) float Wt[16][132];
    const int t = threadIdx.x;
    const int m0 = blockIdx.x * 64;
    const int tx = t & 15, ty = t >> 4;

    float acc[4][8];
#pragma unroll
    for(int i=0;i<4;i++)
#pragma unroll
        for(int j=0;j<8;j++) acc[i][j]=0.f;

    const int ar = t>>2, akq = (t&3)*4;
    const int wo = t>>1, wkq = (t&1)*8;

    for(int kc=0;kc<128;kc+=16){
        float4 av = *(const float4*)(msg0 + (size_t)(m0+ar)*128 + kc + akq);
        At[akq+0][ar] = av.x;
        At[akq+1][ar] = av.y;
        At[akq+2][ar] = av.z;
        At[akq+3][ar] = av.w;
        float4 w0 = *(const float4*)(Wo + (size_t)wo*128 + kc + wkq);
        float4 w1 = *(const float4*)(Wo + (size_t)wo*128 + kc + wkq + 4);
        Wt[wkq+0][wo] = w0.x; Wt[wkq+1][wo] = w0.y;
        Wt[wkq+2][wo] = w0.z; Wt[wkq+3][wo] = w0.w;
        Wt[wkq+4][wo] = w1.x; Wt[wkq+5][wo] = w1.y;
        Wt[wkq+6][wo] = w1.z; Wt[wkq+7][wo] = w1.w;
        __syncthreads();
#pragma unroll
        for(int kk=0;kk<16;kk++){
            float4 a4 = *(const float4*)&At[kk][ty*4];
            float4 wa = *(const float4*)&Wt[kk][tx*4];
            float4 wb = *(const float4*)&Wt[kk][64 + tx*4];
            float avr[4] = {a4.x,a4.y,a4.z,a4.w};
            float wvr[8] = {wa.x,wa.y,wa.z,wa.w, wb.x,wb.y,wb.z,wb.w};
#pragma unroll
            for(int i=0;i<4;i++)
#pragma unroll
                for(int j=0;j<8;j++) acc[i][j] += avr[i]*wvr[j];
        }
        __syncthreads();
    }
#pragma unroll
    for(int i=0;i<4;i++){
        int m = m0 + ty*4 + i;
#pragma unroll
        for(int j=0;j<8;j++){
            int o = (j<4)? (tx*4+j) : (64 + tx*4 + (j-4));
            out[(size_t)m*128 + o] = acc[i][j] + bo[o];
        }
    }
}

extern "C" void kernel_launch(void* const* d_in, const int* in_sizes, int n_in,
                              void* d_out, int out_size, void* d_ws, size_t ws_size,
                              hipStream_t stream) {
    const float* x  = (const float*)d_in[0];
    const float* tg = (const float*)d_in[1];
    const float* Wq = (const float*)d_in[2];
    const float* Wk = (const float*)d_in[3];
    const float* Wv = (const float*)d_in[4];
    const float* Wo = (const float*)d_in[5];
    const float* bo = (const float*)d_in[6];

    float* ws = (float*)d_ws;
    float* q0   = ws + 0;
    float* k0   = ws + 2359296;
    float* v0   = ws + 4718592;
    float* q1   = ws + 7077888;
    float* k1   = ws + 7667712;
    float* v1   = ws + 8257536;
    float* q2   = ws + 8847360;
    float* k2   = ws + 8994816;
    float* v2   = ws + 9142272;
    float* msg2 = ws + 9289728;
    float* msg1 = ws + 9437184;
    float* msg0 = ws + 10027008;
    int*   idx2 = (int*)(ws + 12386304);
    int*   idx1 = (int*)(ws + 12533760);

    k_proj<<<dim3(288,3), 256, 0, stream>>>(x, tg, Wq, Wk, Wv, q0, k0, v0);
    k_pool<<<442368/256, 256, 0, stream>>>((const float4*)q0, (float4*)q1, 96, N0, N1, 442368);
    k_pool<<<110592/256, 256, 0, stream>>>((const float4*)q1, (float4*)q2, 48, N1, N2, 110592);
    k_attn2<<<dim3(16,9), 256, 0, stream>>>(q2, k2, v2, msg2, idx2);
    k_ref1<<<9216, 256, 0, stream>>>(q1, k1, v1, msg2, idx2, msg1, idx1);
    k_ref0<<<18432, 256, 0, stream>>>(q0, k0, v0, msg1, idx1, msg0);
    k_out<<<288, 256, 0, stream>>>(msg0, Wo, bo, (float*)d_out);
}

// Round 3
// 357.476 us; speedup vs baseline: 1.4885x; 1.4885x over previous
//
#include <hip/hip_runtime.h>

#define NB   2
#define NHD  8
#define BH   16
#define HD   16
#define N0   9216
#define N1   2304
#define N2   576
#define W0_  96
#define W1_  48
#define W2_  24
#define M_TOT 18432
#define TEMP 0.25f

// ---------------- projection GEMM: dst[(b,h,n,d)] = sum_c A[m][c] * W[o][c] ----------------
__global__ __launch_bounds__(256) void k_proj(const float* __restrict__ x, const float* __restrict__ tg,
    const float* __restrict__ Wq, const float* __restrict__ Wk, const float* __restrict__ Wv,
    float* __restrict__ q0, float* __restrict__ k0, float* __restrict__ v0)
{
    __shared__ __align__(16) float At[16][68];   // [k][row]
    __shared__ __align__(16) float Wt[16][132];  // [k][o]
    const int t = threadIdx.x;
    const int which = blockIdx.y;
    const float* A  = (which==0)? x : tg;
    const float* Wm = (which==0)? Wq : (which==1? Wk : Wv);
    float* dst      = (which==0)? q0 : (which==1? k0 : v0);
    const int m0 = blockIdx.x * 64;
    const int tx = t & 15, ty = t >> 4;

    float acc[4][8];
#pragma unroll
    for(int i=0;i<4;i++)
#pragma unroll
        for(int j=0;j<8;j++) acc[i][j]=0.f;

    const int ar = t>>2, akq = (t&3)*4;
    const int wo = t>>1, wkq = (t&1)*8;

    for(int kc=0;kc<128;kc+=16){
        // stage A tile (transposed): At[k][row]
        float4 av = *(const float4*)(A + (size_t)(m0+ar)*128 + kc + akq);
        At[akq+0][ar] = av.x;
        At[akq+1][ar] = av.y;
        At[akq+2][ar] = av.z;
        At[akq+3][ar] = av.w;
        // stage W tile (transposed): Wt[k][o]
        float4 w0 = *(const float4*)(Wm + (size_t)wo*128 + kc + wkq);
        float4 w1 = *(const float4*)(Wm + (size_t)wo*128 + kc + wkq + 4);
        Wt[wkq+0][wo] = w0.x; Wt[wkq+1][wo] = w0.y;
        Wt[wkq+2][wo] = w0.z; Wt[wkq+3][wo] = w0.w;
        Wt[wkq+4][wo] = w1.x; Wt[wkq+5][wo] = w1.y;
        Wt[wkq+6][wo] = w1.z; Wt[wkq+7][wo] = w1.w;
        __syncthreads();
#pragma unroll
        for(int kk=0;kk<16;kk++){
            float4 a4 = *(const float4*)&At[kk][ty*4];
            float4 wa = *(const float4*)&Wt[kk][tx*4];
            float4 wb = *(const float4*)&Wt[kk][64 + tx*4];
            float avr[4] = {a4.x,a4.y,a4.z,a4.w};
            float wvr[8] = {wa.x,wa.y,wa.z,wa.w, wb.x,wb.y,wb.z,wb.w};
#pragma unroll
            for(int i=0;i<4;i++)
#pragma unroll
                for(int j=0;j<8;j++) acc[i][j] += avr[i]*wvr[j];
        }
        __syncthreads();
    }
#pragma unroll
    for(int i=0;i<4;i++){
        int m = m0 + ty*4 + i;
        int b = m / N0; int n = m - b*N0;
#pragma unroll
        for(int j=0;j<8;j++){
            int o = (j<4)? (tx*4+j) : (64 + tx*4 + (j-4));
            int h = o>>4, d = o&15;
            dst[((size_t)(b*NHD+h)*N0 + n)*16 + d] = acc[i][j];
        }
    }
}

// ---------------- 2x2 average pooling, treats q/k/v contiguously as [48][Nin][16] ----------------
__global__ __launch_bounds__(256) void k_pool(const float4* __restrict__ src, float4* __restrict__ dst,
                                              int Win, int Nin, int Nout, int total)
{
    int tid = blockIdx.x*256 + threadIdx.x;
    if (tid >= total) return;
    int d4 = tid & 3;
    int rest = tid >> 2;
    int n = rest % Nout; int g = rest / Nout;
    int Wout = Win>>1;
    int yo = n / Wout, xo = n - yo*Wout;
    int cbase = (2*yo)*Win + 2*xo;
    const float4* s = src + (size_t)g*Nin*4;
    float4 a = s[(cbase      )*4 + d4];
    float4 b = s[(cbase+1    )*4 + d4];
    float4 c = s[(cbase+Win  )*4 + d4];
    float4 d = s[(cbase+Win+1)*4 + d4];
    float4 o;
    o.x = 0.25f*(a.x+b.x+c.x+d.x);
    o.y = 0.25f*(a.y+b.y+c.y+d.y);
    o.z = 0.25f*(a.z+b.z+c.z+d.z);
    o.w = 0.25f*(a.w+b.w+c.w+d.w);
    dst[((size_t)g*Nout + n)*4 + d4] = o;
}

// ---------------- level-2 full attention + top-16: ONE QUERY PER WAVE ----------------
__global__ __launch_bounds__(256) void k_attn2(const float* __restrict__ q2, const float* __restrict__ k2,
    const float* __restrict__ v2, float* __restrict__ msg2, int* __restrict__ idx2)
{
    __shared__ __align__(16) float kT[16][577];
    const int bh = blockIdx.x;
    const int qt = blockIdx.y;       // 0..143, 4 queries per block
    const int t = threadIdx.x;
    // stage k2 transposed: kT[d][m]
    const float4* kg = (const float4*)(k2 + (size_t)bh*N2*16);
#pragma unroll
    for(int i=0;i<9;i++){
        int f = i*256 + t;          // 2304 float4s
        int m = f>>2, dq = (f&3)*4;
        float4 kv = kg[f];
        kT[dq+0][m]=kv.x; kT[dq+1][m]=kv.y; kT[dq+2][m]=kv.z; kT[dq+3][m]=kv.w;
    }
    __syncthreads();

    const int wv = t>>6, lane = t&63;
    const float4* vg = (const float4*)(v2 + (size_t)bh*N2*16);

    const int q = qt*4 + wv;        // one query per wave
    const float* qp = q2 + ((size_t)bh*N2 + q)*16;
    float qr[16];
#pragma unroll
    for(int d=0; d<16; d+=4){
        float4 qq = *(const float4*)(qp+d);
        qr[d]=qq.x; qr[d+1]=qq.y; qr[d+2]=qq.z; qr[d+3]=qq.w;
    }
    float ev[9];
    float mx = -1e30f;
#pragma unroll
    for(int t9=0;t9<9;t9++){
        int m = t9*64 + lane;
        float s = 0.f;
#pragma unroll
        for(int d=0;d<16;d++) s += qr[d]*kT[d][m];
        s *= TEMP;
        ev[t9]=s;
        mx = fmaxf(mx, s);
    }
#pragma unroll
    for(int st=1; st<64; st<<=1) mx = fmaxf(mx, __shfl_xor(mx, st));
    float sum=0.f;
#pragma unroll
    for(int t9=0;t9<9;t9++){ ev[t9] = expf(ev[t9]-mx); sum += ev[t9]; }
#pragma unroll
    for(int st=1; st<64; st<<=1) sum += __shfl_xor(sum, st);

    float acc[16];
#pragma unroll
    for(int d=0;d<16;d++) acc[d]=0.f;
#pragma unroll
    for(int t9=0;t9<9;t9++){
        int m = t9*64+lane;
        float e = ev[t9];
#pragma unroll
        for(int dq=0; dq<4; dq++){
            float4 vvv = vg[m*4+dq];
            acc[dq*4+0] += e*vvv.x; acc[dq*4+1] += e*vvv.y;
            acc[dq*4+2] += e*vvv.z; acc[dq*4+3] += e*vvv.w;
        }
    }
#pragma unroll
    for(int st=1; st<64; st<<=1){
#pragma unroll
        for(int d=0;d<16;d++) acc[d] += __shfl_xor(acc[d], st);
    }
    float inv = 1.0f/sum;
    if (lane==0){
        float4* mp = (float4*)(msg2 + ((size_t)bh*N2+q)*16);
#pragma unroll
        for(int dq=0;dq<4;dq++){
            float4 o;
            o.x=acc[dq*4+0]*inv; o.y=acc[dq*4+1]*inv;
            o.z=acc[dq*4+2]*inv; o.w=acc[dq*4+3]*inv;
            mp[dq]=o;
        }
    }
    // top-16 (order of exp == order of scores; ties -> lowest index)
    int* ip = idx2 + ((size_t)bh*N2+q)*16;
    for(int it=0; it<16; it++){
        float bv = ev[0]; int bt=0;
#pragma unroll
        for(int t9=1;t9<9;t9++){ if (ev[t9] > bv){ bv=ev[t9]; bt=t9; } }
        int bm = bt*64 + lane;
#pragma unroll
        for(int st=1; st<64; st<<=1){
            float ov = __shfl_xor(bv, st);
            int   om = __shfl_xor(bm, st);
            if (ov > bv || (ov==bv && om < bm)){ bv=ov; bm=om; }
        }
        if (lane==0) ip[it] = bm;
        int bt9 = bm>>6;
#pragma unroll
        for(int t9=0;t9<9;t9++)
            if (t9==bt9 && (bm & 63) == lane) ev[t9] = -1e30f;
    }
}

// ---------------- level-1 refinement (64 candidates/query) + top-8 ----------------
__global__ __launch_bounds__(256) void k_ref1(const float* __restrict__ q1, const float* __restrict__ k1,
    const float* __restrict__ v1, const float* __restrict__ msg2, const int* __restrict__ idx2,
    float* __restrict__ msg1, int* __restrict__ idx1)
{
    const int gw = blockIdx.x*4 + (threadIdx.x>>6);
    const int lane = threadIdx.x & 63;
    const int bh = gw / N1, n = gw - bh*N1;
    const int y = n / W1_, x = n - y*W1_;
    const int par = (y>>1)*W2_ + (x>>1);
    const int kk = lane>>2, tt = lane&3, dy = tt>>1, dx = tt&1;
    int p = idx2[((size_t)bh*N2+par)*16 + kk];
    int ky = p / W2_, kx = p - ky*W2_;
    int child = (2*ky+dy)*W1_ + 2*kx+dx;

    const float* qp = q1 + ((size_t)bh*N1+n)*16;
    float qr[16];
#pragma unroll
    for(int d=0; d<16; d+=4){
        float4 qq = *(const float4*)(qp+d);
        qr[d]=qq.x; qr[d+1]=qq.y; qr[d+2]=qq.z; qr[d+3]=qq.w;
    }
    const float4* kp = (const float4*)(k1 + ((size_t)bh*N1+child)*16);
    float s = 0.f;
#pragma unroll
    for(int dq=0;dq<4;dq++){
        float4 kv = kp[dq];
        s += qr[dq*4+0]*kv.x + qr[dq*4+1]*kv.y + qr[dq*4+2]*kv.z + qr[dq*4+3]*kv.w;
    }
    s *= TEMP;
    float mx = s;
#pragma unroll
    for(int st=1; st<64; st<<=1) mx = fmaxf(mx, __shfl_xor(mx, st));
    float e = expf(s - mx);
    float sum = e;
#pragma unroll
    for(int st=1; st<64; st<<=1) sum += __shfl_xor(sum, st);

    float acc[16];
    const float4* vp = (const float4*)(v1 + ((size_t)bh*N1+child)*16);
#pragma unroll
    for(int dq=0;dq<4;dq++){
        float4 vv = vp[dq];
        acc[dq*4+0]=e*vv.x; acc[dq*4+1]=e*vv.y; acc[dq*4+2]=e*vv.z; acc[dq*4+3]=e*vv.w;
    }
#pragma unroll
    for(int st=1; st<64; st<<=1){
#pragma unroll
        for(int d=0;d<16;d++) acc[d] += __shfl_xor(acc[d], st);
    }
    float inv = 1.0f/sum;
    if (lane==0){
        const float4* m2 = (const float4*)(msg2 + ((size_t)bh*N2+par)*16);
        float4* m1 = (float4*)(msg1 + ((size_t)bh*N1+n)*16);
#pragma unroll
        for(int dq=0;dq<4;dq++){
            float4 mm = m2[dq];
            float4 o;
            o.x = mm.x + acc[dq*4+0]*inv; o.y = mm.y + acc[dq*4+1]*inv;
            o.z = mm.z + acc[dq*4+2]*inv; o.w = mm.w + acc[dq*4+3]*inv;
            m1[dq]=o;
        }
    }
    // top-8 over the 64 candidates (ties -> lowest candidate position)
    int* ip = idx1 + ((size_t)bh*N1+n)*8;
    float ee = e;
    for(int it=0; it<8; it++){
        float bv = ee; int bj = lane;
#pragma unroll
        for(int st=1; st<64; st<<=1){
            float ov = __shfl_xor(bv, st);
            int   oj = __shfl_xor(bj, st);
            if (ov > bv || (ov==bv && oj < bj)){ bv=ov; bj=oj; }
        }
        int wc = __shfl(child, bj);
        if (lane==0) ip[it] = wc;
        if (lane == bj) ee = -1e30f;
    }
}

// ---------------- level-0 refinement (32 candidates/query), 2 queries per wave ----------------
__global__ __launch_bounds__(256) void k_ref0(const float* __restrict__ q0, const float* __restrict__ k0,
    const float* __restrict__ v0, const float* __restrict__ msg1, const int* __restrict__ idx1,
    float* __restrict__ msg0)
{
    const int gw = blockIdx.x*4 + (threadIdx.x>>6);
    const int lane = threadIdx.x & 63;
    const int sub = lane>>5, j = lane&31;
    const int qi = gw*2 + sub;
    const int bh = qi / N0, n = qi - bh*N0;
    const int y = n / W0_, x = n - y*W0_;
    const int par = (y>>1)*W1_ + (x>>1);
    const int kk = j>>2, tt = j&3, dy = tt>>1, dx = tt&1;
    int p = idx1[((size_t)bh*N1+par)*8 + kk];
    int ky = p / W1_, kx = p - ky*W1_;
    int child = (2*ky+dy)*W0_ + 2*kx+dx;

    const float* qp = q0 + ((size_t)bh*N0+n)*16;
    float qr[16];
#pragma unroll
    for(int d=0; d<16; d+=4){
        float4 qq = *(const float4*)(qp+d);
        qr[d]=qq.x; qr[d+1]=qq.y; qr[d+2]=qq.z; qr[d+3]=qq.w;
    }
    const float4* kp = (const float4*)(k0 + ((size_t)bh*N0+child)*16);
    float s = 0.f;
#pragma unroll
    for(int dq=0;dq<4;dq++){
        float4 kv = kp[dq];
        s += qr[dq*4+0]*kv.x + qr[dq*4+1]*kv.y + qr[dq*4+2]*kv.z + qr[dq*4+3]*kv.w;
    }
    s *= TEMP;
    float mx = s;
#pragma unroll
    for(int st=1; st<32; st<<=1) mx = fmaxf(mx, __shfl_xor(mx, st));
    float e = expf(s - mx);
    float sum = e;
#pragma unroll
    for(int st=1; st<32; st<<=1) sum += __shfl_xor(sum, st);

    float acc[16];
    const float4* vp = (const float4*)(v0 + ((size_t)bh*N0+child)*16);
#pragma unroll
    for(int dq=0;dq<4;dq++){
        float4 vv = vp[dq];
        acc[dq*4+0]=e*vv.x; acc[dq*4+1]=e*vv.y; acc[dq*4+2]=e*vv.z; acc[dq*4+3]=e*vv.w;
    }
#pragma unroll
    for(int st=1; st<32; st<<=1){
#pragma unroll
        for(int d=0;d<16;d++) acc[d] += __shfl_xor(acc[d], st);
    }
    float inv = 1.0f/sum;
    if (j==0){
        int b = bh>>3, h = bh&7;
        const float4* m1 = (const float4*)(msg1 + ((size_t)bh*N1+par)*16);
        float4* mp = (float4*)(msg0 + ((size_t)b*N0+n)*128 + h*16);
#pragma unroll
        for(int dq=0;dq<4;dq++){
            float4 mm = m1[dq];
            float4 o;
            o.x = mm.x + acc[dq*4+0]*inv; o.y = mm.y + acc[dq*4+1]*inv;
            o.z = mm.z + acc[dq*4+2]*inv; o.w = mm.w + acc[dq*4+3]*inv;
            mp[dq]=o;
        }
    }
}

// ---------------- output projection GEMM + bias ----------------
__global__ __launch_bounds__(256) void k_out(const float* __restrict__ msg0, const float* __restrict__ Wo,
    const float* __restrict__ bo, float* __restrict__ out)
{
    __shared__ __align__(16) float At[16][68];
    __shared__ __align__(16) float Wt[16][132];
    const int t = threadIdx.x;
    const int m0 = blockIdx.x * 64;
    const int tx = t & 15, ty = t >> 4;

    float acc[4][8];
#pragma unroll
    for(int i=0;i<4;i++)
#pragma unroll
        for(int j=0;j<8;j++) acc[i][j]=0.f;

    const int ar = t>>2, akq = (t&3)*4;
    const int wo = t>>1, wkq = (t&1)*8;

    for(int kc=0;kc<128;kc+=16){
        float4 av = *(const float4*)(msg0 + (size_t)(m0+ar)*128 + kc + akq);
        At[akq+0][ar] = av.x;
        At[akq+1][ar] = av.y;
        At[akq+2][ar] = av.z;
        At[akq+3][ar] = av.w;
        float4 w0 = *(const float4*)(Wo + (size_t)wo*128 + kc + wkq);
        float4 w1 = *(const float4*)(Wo + (size_t)wo*128 + kc + wkq + 4);
        Wt[wkq+0][wo] = w0.x; Wt[wkq+1][wo] = w0.y;
        Wt[wkq+2][wo] = w0.z; Wt[wkq+3][wo] = w0.w;
        Wt[wkq+4][wo] = w1.x; Wt[wkq+5][wo] = w1.y;
        Wt[wkq+6][wo] = w1.z; Wt[wkq+7][wo] = w1.w;
        __syncthreads();
#pragma unroll
        for(int kk=0;kk<16;kk++){
            float4 a4 = *(const float4*)&At[kk][ty*4];
            float4 wa = *(const float4*)&Wt[kk][tx*4];
            float4 wb = *(const float4*)&Wt[kk][64 + tx*4];
            float avr[4] = {a4.x,a4.y,a4.z,a4.w};
            float wvr[8] = {wa.x,wa.y,wa.z,wa.w, wb.x,wb.y,wb.z,wb.w};
#pragma unroll
            for(int i=0;i<4;i++)
#pragma unroll
                for(int j=0;j<8;j++) acc[i][j] += avr[i]*wvr[j];
        }
        __syncthreads();
    }
#pragma unroll
    for(int i=0;i<4;i++){
        int m = m0 + ty*4 + i;
#pragma unroll
        for(int j=0;j<8;j++){
            int o = (j<4)? (tx*4+j) : (64 + tx*4 + (j-4));
            out[(size_t)m*128 + o] = acc[i][j] + bo[o];
        }
    }
}

extern "C" void kernel_launch(void* const* d_in, const int* in_sizes, int n_in,
                              void* d_out, int out_size, void* d_ws, size_t ws_size,
                              hipStream_t stream) {
    const float* x  = (const float*)d_in[0];
    const float* tg = (const float*)d_in[1];
    const float* Wq = (const float*)d_in[2];
    const float* Wk = (const float*)d_in[3];
    const float* Wv = (const float*)d_in[4];
    const float* Wo = (const float*)d_in[5];
    const float* bo = (const float*)d_in[6];

    float* ws = (float*)d_ws;
    float* q0   = ws + 0;
    float* k0   = ws + 2359296;
    float* v0   = ws + 4718592;
    float* q1   = ws + 7077888;
    float* k1   = ws + 7667712;
    float* v1   = ws + 8257536;
    float* q2   = ws + 8847360;
    float* k2   = ws + 8994816;
    float* v2   = ws + 9142272;
    float* msg2 = ws + 9289728;
    float* msg1 = ws + 9437184;
    float* msg0 = ws + 10027008;
    int*   idx2 = (int*)(ws + 12386304);
    int*   idx1 = (int*)(ws + 12533760);

    k_proj<<<dim3(288,3), 256, 0, stream>>>(x, tg, Wq, Wk, Wv, q0, k0, v0);
    k_pool<<<442368/256, 256, 0, stream>>>((const float4*)q0, (float4*)q1, 96, N0, N1, 442368);
    k_pool<<<110592/256, 256, 0, stream>>>((const float4*)q1, (float4*)q2, 48, N1, N2, 110592);
    k_attn2<<<dim3(16,144), 256, 0, stream>>>(q2, k2, v2, msg2, idx2);
    k_ref1<<<9216, 256, 0, stream>>>(q1, k1, v1, msg2, idx2, msg1, idx1);
    k_ref0<<<18432, 256, 0, stream>>>(q0, k0, v0, msg1, idx1, msg0);
    k_out<<<288, 256, 0, stream>>>(msg0, Wo, bo, (float*)d_out);
}

// Round 4
// 288.926 us; speedup vs baseline: 1.8417x; 1.2373x over previous
//
#include <hip/hip_runtime.h>

#define NB   2
#define NHD  8
#define BH   16
#define HD   16
#define N0   9216
#define N1   2304
#define N2   576
#define W0_  96
#define W1_  48
#define W2_  24
#define M_TOT 18432
#define TEMP 0.25f

// ---------------- projection GEMM: dst[(b,h,n,d)] = sum_c A[m][c] * W[o][c] ----------------
__global__ __launch_bounds__(256) void k_proj(const float* __restrict__ x, const float* __restrict__ tg,
    const float* __restrict__ Wq, const float* __restrict__ Wk, const float* __restrict__ Wv,
    float* __restrict__ q0, float* __restrict__ k0, float* __restrict__ v0)
{
    __shared__ __align__(16) float At[16][68];   // [k][row]
    __shared__ __align__(16) float Wt[16][132];  // [k][o]
    const int t = threadIdx.x;
    const int which = blockIdx.y;
    const float* A  = (which==0)? x : tg;
    const float* Wm = (which==0)? Wq : (which==1? Wk : Wv);
    float* dst      = (which==0)? q0 : (which==1? k0 : v0);
    const int m0 = blockIdx.x * 64;
    const int tx = t & 15, ty = t >> 4;

    float acc[4][8];
#pragma unroll
    for(int i=0;i<4;i++)
#pragma unroll
        for(int j=0;j<8;j++) acc[i][j]=0.f;

    const int ar = t>>2, akq = (t&3)*4;
    const int wo = t>>1, wkq = (t&1)*8;

    for(int kc=0;kc<128;kc+=16){
        float4 av = *(const float4*)(A + (size_t)(m0+ar)*128 + kc + akq);
        At[akq+0][ar] = av.x;
        At[akq+1][ar] = av.y;
        At[akq+2][ar] = av.z;
        At[akq+3][ar] = av.w;
        float4 w0 = *(const float4*)(Wm + (size_t)wo*128 + kc + wkq);
        float4 w1 = *(const float4*)(Wm + (size_t)wo*128 + kc + wkq + 4);
        Wt[wkq+0][wo] = w0.x; Wt[wkq+1][wo] = w0.y;
        Wt[wkq+2][wo] = w0.z; Wt[wkq+3][wo] = w0.w;
        Wt[wkq+4][wo] = w1.x; Wt[wkq+5][wo] = w1.y;
        Wt[wkq+6][wo] = w1.z; Wt[wkq+7][wo] = w1.w;
        __syncthreads();
#pragma unroll
        for(int kk=0;kk<16;kk++){
            float4 a4 = *(const float4*)&At[kk][ty*4];
            float4 wa = *(const float4*)&Wt[kk][tx*4];
            float4 wb = *(const float4*)&Wt[kk][64 + tx*4];
            float avr[4] = {a4.x,a4.y,a4.z,a4.w};
            float wvr[8] = {wa.x,wa.y,wa.z,wa.w, wb.x,wb.y,wb.z,wb.w};
#pragma unroll
            for(int i=0;i<4;i++)
#pragma unroll
                for(int j=0;j<8;j++) acc[i][j] += avr[i]*wvr[j];
        }
        __syncthreads();
    }
#pragma unroll
    for(int i=0;i<4;i++){
        int m = m0 + ty*4 + i;
        int b = m / N0; int n = m - b*N0;
#pragma unroll
        for(int j=0;j<8;j++){
            int o = (j<4)? (tx*4+j) : (64 + tx*4 + (j-4));
            int h = o>>4, d = o&15;
            dst[((size_t)(b*NHD+h)*N0 + n)*16 + d] = acc[i][j];
        }
    }
}

// ---------------- 2x2 average pooling, treats q/k/v contiguously as [48][Nin][16] ----------------
__global__ __launch_bounds__(256) void k_pool(const float4* __restrict__ src, float4* __restrict__ dst,
                                              int Win, int Nin, int Nout, int total)
{
    int tid = blockIdx.x*256 + threadIdx.x;
    if (tid >= total) return;
    int d4 = tid & 3;
    int rest = tid >> 2;
    int n = rest % Nout; int g = rest / Nout;
    int Wout = Win>>1;
    int yo = n / Wout, xo = n - yo*Wout;
    int cbase = (2*yo)*Win + 2*xo;
    const float4* s = src + (size_t)g*Nin*4;
    float4 a = s[(cbase      )*4 + d4];
    float4 b = s[(cbase+1    )*4 + d4];
    float4 c = s[(cbase+Win  )*4 + d4];
    float4 d = s[(cbase+Win+1)*4 + d4];
    float4 o;
    o.x = 0.25f*(a.x+b.x+c.x+d.x);
    o.y = 0.25f*(a.y+b.y+c.y+d.y);
    o.z = 0.25f*(a.z+b.z+c.z+d.z);
    o.w = 0.25f*(a.w+b.w+c.w+d.w);
    dst[((size_t)g*Nout + n)*4 + d4] = o;
}

// ---------------- level-2 full attention + top-16: ONE QUERY PER WAVE ----------------
__global__ __launch_bounds__(256) void k_attn2(const float* __restrict__ q2, const float* __restrict__ k2,
    const float* __restrict__ v2, float* __restrict__ msg2, int* __restrict__ idx2)
{
    __shared__ __align__(16) float kT[16][577];
    const int bh = blockIdx.x;
    const int qt = blockIdx.y;       // 0..143, 4 queries per block
    const int t = threadIdx.x;
    const float4* kg = (const float4*)(k2 + (size_t)bh*N2*16);
#pragma unroll
    for(int i=0;i<9;i++){
        int f = i*256 + t;          // 2304 float4s
        int m = f>>2, dq = (f&3)*4;
        float4 kv = kg[f];
        kT[dq+0][m]=kv.x; kT[dq+1][m]=kv.y; kT[dq+2][m]=kv.z; kT[dq+3][m]=kv.w;
    }
    __syncthreads();

    const int wv = t>>6, lane = t&63;
    const float4* vg = (const float4*)(v2 + (size_t)bh*N2*16);

    const int q = qt*4 + wv;        // one query per wave
    const float* qp = q2 + ((size_t)bh*N2 + q)*16;
    float qr[16];
#pragma unroll
    for(int d=0; d<16; d+=4){
        float4 qq = *(const float4*)(qp+d);
        qr[d]=qq.x; qr[d+1]=qq.y; qr[d+2]=qq.z; qr[d+3]=qq.w;
    }
    float ev[9];
    float mx = -1e30f;
#pragma unroll
    for(int t9=0;t9<9;t9++){
        int m = t9*64 + lane;
        float s = 0.f;
#pragma unroll
        for(int d=0;d<16;d++) s += qr[d]*kT[d][m];
        s *= TEMP;
        ev[t9]=s;
        mx = fmaxf(mx, s);
    }
#pragma unroll
    for(int st=1; st<64; st<<=1) mx = fmaxf(mx, __shfl_xor(mx, st));
    float sum=0.f;
#pragma unroll
    for(int t9=0;t9<9;t9++){ ev[t9] = expf(ev[t9]-mx); sum += ev[t9]; }
#pragma unroll
    for(int st=1; st<64; st<<=1) sum += __shfl_xor(sum, st);

    float acc[16];
#pragma unroll
    for(int d=0;d<16;d++) acc[d]=0.f;
#pragma unroll
    for(int t9=0;t9<9;t9++){
        int m = t9*64+lane;
        float e = ev[t9];
#pragma unroll
        for(int dq=0; dq<4; dq++){
            float4 vvv = vg[m*4+dq];
            acc[dq*4+0] += e*vvv.x; acc[dq*4+1] += e*vvv.y;
            acc[dq*4+2] += e*vvv.z; acc[dq*4+3] += e*vvv.w;
        }
    }
    // dim-splitting butterfly reduction: lane ends with O[lane>>2]
    const bool b5 = (lane & 32) != 0;
    float r8[8];
#pragma unroll
    for(int i=0;i<8;i++){
        float snd  = b5 ? acc[i]   : acc[i+8];
        float kept = b5 ? acc[i+8] : acc[i];
        r8[i] = kept + __shfl_xor(snd, 32);
    }
    const bool b4 = (lane & 16) != 0;
    float r4[4];
#pragma unroll
    for(int i=0;i<4;i++){
        float snd  = b4 ? r8[i]   : r8[i+4];
        float kept = b4 ? r8[i+4] : r8[i];
        r4[i] = kept + __shfl_xor(snd, 16);
    }
    const bool b3 = (lane & 8) != 0;
    float r2[2];
#pragma unroll
    for(int i=0;i<2;i++){
        float snd  = b3 ? r4[i]   : r4[i+2];
        float kept = b3 ? r4[i+2] : r4[i];
        r2[i] = kept + __shfl_xor(snd, 8);
    }
    const bool b2 = (lane & 4) != 0;
    {
        float snd  = b2 ? r2[0] : r2[1];
        float kept = b2 ? r2[1] : r2[0];
        r2[0] = kept + __shfl_xor(snd, 4);
    }
    r2[0] += __shfl_xor(r2[0], 2);
    r2[0] += __shfl_xor(r2[0], 1);

    float inv = 1.0f/sum;
    if ((lane&3)==0){
        msg2[((size_t)bh*N2+q)*16 + (lane>>2)] = r2[0]*inv;
    }
    // top-16 (ties -> lowest index)
    int* ip = idx2 + ((size_t)bh*N2+q)*16;
    for(int it=0; it<16; it++){
        float bv = ev[0]; int bt=0;
#pragma unroll
        for(int t9=1;t9<9;t9++){ if (ev[t9] > bv){ bv=ev[t9]; bt=t9; } }
        int bm = bt*64 + lane;
#pragma unroll
        for(int st=1; st<64; st<<=1){
            float ov = __shfl_xor(bv, st);
            int   om = __shfl_xor(bm, st);
            if (ov > bv || (ov==bv && om < bm)){ bv=ov; bm=om; }
        }
        if (lane==0) ip[it] = bm;
        int bt9 = bm>>6;
#pragma unroll
        for(int t9=0;t9<9;t9++)
            if (t9==bt9 && (bm & 63) == lane) ev[t9] = -1e30f;
    }
}

// ---------------- level-1 refinement (64 candidates/query) + rank-based top-8 ----------------
__global__ __launch_bounds__(256) void k_ref1(const float* __restrict__ q1, const float* __restrict__ k1,
    const float* __restrict__ v1, const float* __restrict__ msg2, const int* __restrict__ idx2,
    float* __restrict__ msg1, int* __restrict__ idx1)
{
    const int gw = blockIdx.x*4 + (threadIdx.x>>6);
    const int lane = threadIdx.x & 63;
    const int bh = gw / N1, n = gw - bh*N1;
    const int y = n / W1_, x = n - y*W1_;
    const int par = (y>>1)*W2_ + (x>>1);
    const int kk = lane>>2, tt = lane&3, dy = tt>>1, dx = tt&1;
    int p = idx2[((size_t)bh*N2+par)*16 + kk];
    int ky = p / W2_, kx = p - ky*W2_;
    int child = (2*ky+dy)*W1_ + 2*kx+dx;

    const float* qp = q1 + ((size_t)bh*N1+n)*16;
    float qr[16];
#pragma unroll
    for(int d=0; d<16; d+=4){
        float4 qq = *(const float4*)(qp+d);
        qr[d]=qq.x; qr[d+1]=qq.y; qr[d+2]=qq.z; qr[d+3]=qq.w;
    }
    const float4* kp = (const float4*)(k1 + ((size_t)bh*N1+child)*16);
    float s = 0.f;
#pragma unroll
    for(int dq=0;dq<4;dq++){
        float4 kv = kp[dq];
        s += qr[dq*4+0]*kv.x + qr[dq*4+1]*kv.y + qr[dq*4+2]*kv.z + qr[dq*4+3]*kv.w;
    }
    s *= TEMP;
    // softmax without max-subtraction (shift-invariant; |s| is small)
    float e = expf(s);
    float sum = e;
#pragma unroll
    for(int st=1; st<64; st<<=1) sum += __shfl_xor(sum, st);

    float acc[16];
    const float4* vp = (const float4*)(v1 + ((size_t)bh*N1+child)*16);
#pragma unroll
    for(int dq=0;dq<4;dq++){
        float4 vv = vp[dq];
        acc[dq*4+0]=e*vv.x; acc[dq*4+1]=e*vv.y; acc[dq*4+2]=e*vv.z; acc[dq*4+3]=e*vv.w;
    }
    // dim-splitting butterfly: lane ends with O[lane>>2]
    const bool b5 = (lane & 32) != 0;
    float r8[8];
#pragma unroll
    for(int i=0;i<8;i++){
        float snd  = b5 ? acc[i]   : acc[i+8];
        float kept = b5 ? acc[i+8] : acc[i];
        r8[i] = kept + __shfl_xor(snd, 32);
    }
    const bool b4 = (lane & 16) != 0;
    float r4[4];
#pragma unroll
    for(int i=0;i<4;i++){
        float snd  = b4 ? r8[i]   : r8[i+4];
        float kept = b4 ? r8[i+4] : r8[i];
        r4[i] = kept + __shfl_xor(snd, 16);
    }
    const bool b3 = (lane & 8) != 0;
    float r2[2];
#pragma unroll
    for(int i=0;i<2;i++){
        float snd  = b3 ? r4[i]   : r4[i+2];
        float kept = b3 ? r4[i+2] : r4[i];
        r2[i] = kept + __shfl_xor(snd, 8);
    }
    const bool b2 = (lane & 4) != 0;
    {
        float snd  = b2 ? r2[0] : r2[1];
        float kept = b2 ? r2[1] : r2[0];
        r2[0] = kept + __shfl_xor(snd, 4);
    }
    r2[0] += __shfl_xor(r2[0], 2);
    r2[0] += __shfl_xor(r2[0], 1);

    float inv = 1.0f/sum;
    if ((lane&3)==0){
        int d = lane>>2;
        msg1[((size_t)bh*N1+n)*16 + d] =
            msg2[((size_t)bh*N2+par)*16 + d] + r2[0]*inv;
    }

    // rank-based top-8 (stable: ties -> lowest candidate position)
    int cnt = 0;
#pragma unroll
    for(int i=0;i<64;i++){
        float si = __shfl(s, i);
        if (si > s || (si == s && i < lane)) cnt++;
    }
    if (cnt < 8) idx1[((size_t)bh*N1+n)*8 + cnt] = child;
}

// ---------------- level-0 refinement (32 candidates/query), 2 queries per wave ----------------
__global__ __launch_bounds__(256) void k_ref0(const float* __restrict__ q0, const float* __restrict__ k0,
    const float* __restrict__ v0, const float* __restrict__ msg1, const int* __restrict__ idx1,
    float* __restrict__ msg0)
{
    const int gw = blockIdx.x*4 + (threadIdx.x>>6);
    const int lane = threadIdx.x & 63;
    const int sub = lane>>5, j = lane&31;
    const int qi = gw*2 + sub;
    const int bh = qi / N0, n = qi - bh*N0;
    const int y = n / W0_, x = n - y*W0_;
    const int par = (y>>1)*W1_ + (x>>1);
    const int kk = j>>2, tt = j&3, dy = tt>>1, dx = tt&1;
    int p = idx1[((size_t)bh*N1+par)*8 + kk];
    int ky = p / W1_, kx = p - ky*W1_;
    int child = (2*ky+dy)*W0_ + 2*kx+dx;

    const float* qp = q0 + ((size_t)bh*N0+n)*16;
    float qr[16];
#pragma unroll
    for(int d=0; d<16; d+=4){
        float4 qq = *(const float4*)(qp+d);
        qr[d]=qq.x; qr[d+1]=qq.y; qr[d+2]=qq.z; qr[d+3]=qq.w;
    }
    const float4* kp = (const float4*)(k0 + ((size_t)bh*N0+child)*16);
    float s = 0.f;
#pragma unroll
    for(int dq=0;dq<4;dq++){
        float4 kv = kp[dq];
        s += qr[dq*4+0]*kv.x + qr[dq*4+1]*kv.y + qr[dq*4+2]*kv.z + qr[dq*4+3]*kv.w;
    }
    s *= TEMP;
    float e = expf(s);
    float sum = e;
#pragma unroll
    for(int st=1; st<32; st<<=1) sum += __shfl_xor(sum, st);

    float acc[16];
    const float4* vp = (const float4*)(v0 + ((size_t)bh*N0+child)*16);
#pragma unroll
    for(int dq=0;dq<4;dq++){
        float4 vv = vp[dq];
        acc[dq*4+0]=e*vv.x; acc[dq*4+1]=e*vv.y; acc[dq*4+2]=e*vv.z; acc[dq*4+3]=e*vv.w;
    }
    // dim-splitting butterfly over 32-lane group: lane ends with O[(j>>1)&15]
    const bool b4 = (j & 16) != 0;
    float r8[8];
#pragma unroll
    for(int i=0;i<8;i++){
        float snd  = b4 ? acc[i]   : acc[i+8];
        float kept = b4 ? acc[i+8] : acc[i];
        r8[i] = kept + __shfl_xor(snd, 16);
    }
    const bool b3 = (j & 8) != 0;
    float r4[4];
#pragma unroll
    for(int i=0;i<4;i++){
        float snd  = b3 ? r8[i]   : r8[i+4];
        float kept = b3 ? r8[i+4] : r8[i];
        r4[i] = kept + __shfl_xor(snd, 8);
    }
    const bool b2 = (j & 4) != 0;
    float r2[2];
#pragma unroll
    for(int i=0;i<2;i++){
        float snd  = b2 ? r4[i]   : r4[i+2];
        float kept = b2 ? r4[i+2] : r4[i];
        r2[i] = kept + __shfl_xor(snd, 4);
    }
    const bool b1 = (j & 2) != 0;
    {
        float snd  = b1 ? r2[0] : r2[1];
        float kept = b1 ? r2[1] : r2[0];
        r2[0] = kept + __shfl_xor(snd, 2);
    }
    r2[0] += __shfl_xor(r2[0], 1);

    float inv = 1.0f/sum;
    if ((j&1)==0){
        int d = j>>1;
        int b_ = bh>>3, h = bh&7;
        msg0[((size_t)b_*N0+n)*128 + h*16 + d] =
            msg1[((size_t)bh*N1+par)*16 + d] + r2[0]*inv;
    }
}

// ---------------- output projection GEMM + bias ----------------
__global__ __launch_bounds__(256) void k_out(const float* __restrict__ msg0, const float* __restrict__ Wo,
    const float* __restrict__ bo, float* __restrict__ out)
{
    __shared__ __align__(16) float At[16][68];
    __shared__ __align__(16) float Wt[16][132];
    const int t = threadIdx.x;
    const int m0 = blockIdx.x * 64;
    const int tx = t & 15, ty = t >> 4;

    float acc[4][8];
#pragma unroll
    for(int i=0;i<4;i++)
#pragma unroll
        for(int j=0;j<8;j++) acc[i][j]=0.f;

    const int ar = t>>2, akq = (t&3)*4;
    const int wo = t>>1, wkq = (t&1)*8;

    for(int kc=0;kc<128;kc+=16){
        float4 av = *(const float4*)(msg0 + (size_t)(m0+ar)*128 + kc + akq);
        At[akq+0][ar] = av.x;
        At[akq+1][ar] = av.y;
        At[akq+2][ar] = av.z;
        At[akq+3][ar] = av.w;
        float4 w0 = *(const float4*)(Wo + (size_t)wo*128 + kc + wkq);
        float4 w1 = *(const float4*)(Wo + (size_t)wo*128 + kc + wkq + 4);
        Wt[wkq+0][wo] = w0.x; Wt[wkq+1][wo] = w0.y;
        Wt[wkq+2][wo] = w0.z; Wt[wkq+3][wo] = w0.w;
        Wt[wkq+4][wo] = w1.x; Wt[wkq+5][wo] = w1.y;
        Wt[wkq+6][wo] = w1.z; Wt[wkq+7][wo] = w1.w;
        __syncthreads();
#pragma unroll
        for(int kk=0;kk<16;kk++){
            float4 a4 = *(const float4*)&At[kk][ty*4];
            float4 wa = *(const float4*)&Wt[kk][tx*4];
            float4 wb = *(const float4*)&Wt[kk][64 + tx*4];
            float avr[4] = {a4.x,a4.y,a4.z,a4.w};
            float wvr[8] = {wa.x,wa.y,wa.z,wa.w, wb.x,wb.y,wb.z,wb.w};
#pragma unroll
            for(int i=0;i<4;i++)
#pragma unroll
                for(int j=0;j<8;j++) acc[i][j] += avr[i]*wvr[j];
        }
        __syncthreads();
    }
#pragma unroll
    for(int i=0;i<4;i++){
        int m = m0 + ty*4 + i;
#pragma unroll
        for(int j=0;j<8;j++){
            int o = (j<4)? (tx*4+j) : (64 + tx*4 + (j-4));
            out[(size_t)m*128 + o] = acc[i][j] + bo[o];
        }
    }
}

extern "C" void kernel_launch(void* const* d_in, const int* in_sizes, int n_in,
                              void* d_out, int out_size, void* d_ws, size_t ws_size,
                              hipStream_t stream) {
    const float* x  = (const float*)d_in[0];
    const float* tg = (const float*)d_in[1];
    const float* Wq = (const float*)d_in[2];
    const float* Wk = (const float*)d_in[3];
    const float* Wv = (const float*)d_in[4];
    const float* Wo = (const float*)d_in[5];
    const float* bo = (const float*)d_in[6];

    float* ws = (float*)d_ws;
    float* q0   = ws + 0;
    float* k0   = ws + 2359296;
    float* v0   = ws + 4718592;
    float* q1   = ws + 7077888;
    float* k1   = ws + 7667712;
    float* v1   = ws + 8257536;
    float* q2   = ws + 8847360;
    float* k2   = ws + 8994816;
    float* v2   = ws + 9142272;
    float* msg2 = ws + 9289728;
    float* msg1 = ws + 9437184;
    float* msg0 = ws + 10027008;
    int*   idx2 = (int*)(ws + 12386304);
    int*   idx1 = (int*)(ws + 12533760);

    k_proj<<<dim3(288,3), 256, 0, stream>>>(x, tg, Wq, Wk, Wv, q0, k0, v0);
    k_pool<<<442368/256, 256, 0, stream>>>((const float4*)q0, (float4*)q1, 96, N0, N1, 442368);
    k_pool<<<110592/256, 256, 0, stream>>>((const float4*)q1, (float4*)q2, 48, N1, N2, 110592);
    k_attn2<<<dim3(16,144), 256, 0, stream>>>(q2, k2, v2, msg2, idx2);
    k_ref1<<<9216, 256, 0, stream>>>(q1, k1, v1, msg2, idx2, msg1, idx1);
    k_ref0<<<18432, 256, 0, stream>>>(q0, k0, v0, msg1, idx1, msg0);
    k_out<<<288, 256, 0, stream>>>(msg0, Wo, bo, (float*)d_out);
}